// Round 12
// baseline (94.381 us; speedup 1.0000x reference)
//
#include <hip/hip_runtime.h>

#define T_LEN 32768
#define TT 32
#define SWZ(row) ((((row) >> 1) & 7) << 4)

// per-WAVE private LDS region (bytes): xs 48x128, csA 32x128 (z overlays), csB 32x32
#define XS_OFF   0
#define CSA_OFF  6144
#define CSB_OFF  10240
#define WAVE_LDS 11264   // x4 waves = 45056/block; 3 blocks/CU = 135 KB

typedef unsigned short ushort;
typedef unsigned int uint;
typedef __attribute__((ext_vector_type(8))) short short8;   // 8 bf16
typedef __attribute__((ext_vector_type(4))) float f32x4;
typedef __attribute__((ext_vector_type(2))) uint uint2v;

// Fragment-packed bf16 weights (one linear blob, L2-resident, read by all waves).
// ushort layout: [0,32768) A1 full k-steps; [32768,34816) A8 half-frags; [34816,38912) A2.
__device__ __align__(16) ushort g_packAll[38912];

static __device__ __forceinline__ ushort f2bf(float f) {    // RNE f32->bf16
    uint u = __float_as_uint(f);
    u += 0x7fffu + ((u >> 16) & 1u);
    return (ushort)(u >> 16);
}
static __device__ __forceinline__ uint pk2(float a, float b) {
    return (uint)f2bf(a) | ((uint)f2bf(b) << 16);
}

// A-frag (16x16x32): lane l holds A[16m + (l&15)][32s + (l>>4)*8 + j]
__global__ void pack_weights(const float* __restrict__ wconv,
                             const float* __restrict__ wcond,
                             const float* __restrict__ wout) {
    int idx = blockIdx.x * 256 + threadIdx.x;
    if (idx >= 38912) return;
    float v;
    if (idx < 32768) {                   // A1 full k-steps s=0..7 (conv 6 + cond 2)
        int j = idx & 7, lane = (idx >> 3) & 63, f = idx >> 9;  // f = s*8+g
        int s = f >> 3, g = f & 7;
        int row = (g & 3) * 16 + (lane & 15) + ((g & 4) ? 64 : 0);
        int k = s * 32 + (lane >> 4) * 8 + j;
        if (k < 192) v = wconv[row * 192 + (k & 63) * 3 + (k >> 6)];  // tap-major k
        else         v = wcond[row * 80 + (k - 192)];
    } else if (idx < 34816) {            // s=8 half-frags: k = cc 64..79 (l4<2 lanes)
        int e = idx - 32768;
        int j = e & 7, lane32 = (e >> 3) & 31, g = e >> 8;
        int row = (g & 3) * 16 + (lane32 & 15) + ((g & 4) ? 64 : 0);
        v = wcond[row * 80 + 64 + (lane32 >> 4) * 8 + j];
    } else {                             // A2: wout, f2 = s2*4 + m
        int e = idx - 34816;
        int j = e & 7, lane = (e >> 3) & 63, f2 = e >> 9;
        int row = (f2 & 3) * 16 + (lane & 15);
        v = wout[row * 64 + (f2 >> 2) * 32 + (lane >> 4) * 8 + j];
    }
    g_packAll[idx] = f2bf(v);
}

// 2048 blocks x 256 threads; EACH WAVE independently owns one 32-t tile
// (8192 wave-tiles total). Private per-wave LDS; NO __syncthreads anywhere.
// 12 waves/CU (3 blocks) = 12 independent pipelines; any wave's memory stall
// is covered by others in different phases (R3..R11 all plateaued at ~85us
// because barrier-locked waves stalled together).
__global__ __launch_bounds__(256, 3) void wavenet_wave(
    const float* __restrict__ x, const float* __restrict__ cond,
    const float* __restrict__ bconv, const float* __restrict__ bout,
    float* __restrict__ out, float* __restrict__ skip)
{
    __shared__ __align__(16) char lds_all[4 * WAVE_LDS];
    const int tid  = threadIdx.x;
    const int lane = tid & 63, wv = tid >> 6;
    char* lds = lds_all + wv * WAVE_LDS;

    // XCD swizzle (2048 % 8 == 0, bijective): each XCD takes 256 consecutive
    // sBid = one full batch b -> its x+cond stream stays in one L2.
    const int Bk   = blockIdx.x;
    const int sBid = ((Bk & 7) << 8) | (Bk >> 3);
    const int gid  = sBid * 4 + wv;           // wave-tile id in [0, 8192)
    const int b    = gid >> 10;
    const int t0   = (gid & 1023) * TT;

    const int l4 = lane >> 4, l15 = lane & 15;

    // ======== stage tile into private LDS (register transpose, b64 writes) ====
    const int c4  = lane & 15;
    const int qb0 = lane >> 4;
    f32x4 xv[3][4], cav[2][4], cbv[4];
    #pragma unroll
    for (int it = 0; it < 3; ++it) {          // x: 16 ch-quads x 12 t-quads
        int gt = t0 - 16 + (qb0 + it * 4) * 4;
        if (gt >= 0) {
            #pragma unroll
            for (int r = 0; r < 4; ++r)
                xv[it][r] = *(const f32x4*)(x + (size_t)(b * 64 + c4 * 4 + r) * T_LEN + gt);
        } else {
            #pragma unroll
            for (int r = 0; r < 4; ++r) xv[it][r] = (f32x4){0.f, 0.f, 0.f, 0.f};
        }
    }
    #pragma unroll
    for (int it = 0; it < 2; ++it) {          // cond ch 0..63: 16 cq x 8 tq
        int gt = t0 + (qb0 + it * 4) * 4;
        #pragma unroll
        for (int r = 0; r < 4; ++r)
            cav[it][r] = *(const f32x4*)(cond + (size_t)(b * 80 + c4 * 4 + r) * T_LEN + gt);
    }
    if (lane < 32) {                          // cond ch 64..79: 4 cq x 8 tq
        int gt = t0 + (lane >> 2) * 4;
        #pragma unroll
        for (int r = 0; r < 4; ++r)
            cbv[r] = *(const f32x4*)(cond + (size_t)(b * 80 + 64 + (lane & 3) * 4 + r) * T_LEN + gt);
    }

    char* xs  = lds + XS_OFF;
    char* csA = lds + CSA_OFF;
    char* csB = lds + CSB_OFF;
    #pragma unroll
    for (int it = 0; it < 3; ++it) {
        int row0 = (qb0 + it * 4) * 4;
        #pragma unroll
        for (int ts = 0; ts < 4; ++ts) {
            int row = row0 + ts;
            uint2v p = {pk2(xv[it][0][ts], xv[it][1][ts]),
                        pk2(xv[it][2][ts], xv[it][3][ts])};
            *(uint2v*)(xs + row * 128 + ((uint)(c4 * 8) ^ SWZ(row))) = p;
        }
    }
    #pragma unroll
    for (int it = 0; it < 2; ++it) {
        int row0 = (qb0 + it * 4) * 4;
        #pragma unroll
        for (int ts = 0; ts < 4; ++ts) {
            int row = row0 + ts;
            uint2v p = {pk2(cav[it][0][ts], cav[it][1][ts]),
                        pk2(cav[it][2][ts], cav[it][3][ts])};
            *(uint2v*)(csA + row * 128 + ((uint)(c4 * 8) ^ SWZ(row))) = p;
        }
    }
    if (lane < 32) {
        int row0 = (lane >> 2) * 4;
        #pragma unroll
        for (int ts = 0; ts < 4; ++ts) {
            int row = row0 + ts;
            uint2v p = {pk2(cbv[0][ts], cbv[1][ts]), pk2(cbv[2][ts], cbv[3][ts])};
            *(uint2v*)(csB + row * 32 +
                       ((uint)((lane & 3) * 8) ^ ((((uint)row >> 2) & 1) << 4))) = p;
        }
    }

    // ======== phase A: y = conv(*)x + Wcond*c + bconv (M=128, N=32, K=288) ====
    const short8* pW = (const short8*)g_packAll;  // A1 @0, A8 @4096, A2 @4352 (short8 idx)
    const short8 zero8 = (short8){0, 0, 0, 0, 0, 0, 0, 0};

    f32x4 accA[4][2], accG[4][2];
    #pragma unroll
    for (int m = 0; m < 4; ++m) {
        f32x4 ba = *(const f32x4*)(bconv + m * 16 + l4 * 4);
        f32x4 bg = *(const f32x4*)(bconv + 64 + m * 16 + l4 * 4);
        accA[m][0] = ba; accA[m][1] = ba;
        accG[m][0] = bg; accG[m][1] = bg;
    }

    short8 Aa[4], Ag[4];
    #pragma unroll
    for (int m = 0; m < 4; ++m) {
        Aa[m] = pW[m * 64 + lane];
        Ag[m] = pW[(4 + m) * 64 + lane];
    }
    #pragma unroll
    for (int s = 0; s < 9; ++s) {
        short8 An[4], Gn[4];
        #pragma unroll
        for (int m = 0; m < 4; ++m) { An[m] = zero8; Gn[m] = zero8; }
        if (s < 7) {                     // prefetch next full k-step
            #pragma unroll
            for (int m = 0; m < 4; ++m) {
                An[m] = pW[((s + 1) * 8 + m) * 64 + lane];
                Gn[m] = pW[((s + 1) * 8 + 4 + m) * 64 + lane];
            }
        } else if (s == 7) {             // prefetch s=8 half-frags (lanes l4<2)
            if (lane < 32) {
                #pragma unroll
                for (int m = 0; m < 4; ++m) {
                    An[m] = pW[4096 + m * 32 + lane];
                    Gn[m] = pW[4096 + (4 + m) * 32 + lane];
                }
            }
        }
        short8 Bf[2];
        #pragma unroll
        for (int ni = 0; ni < 2; ++ni) {
            int col = ni * 16 + l15;
            if (s < 6) {            // conv tap s>>1, c-half s&1; tap shifts t by 8*tap
                int tl = col + (s >> 1) * 8;
                Bf[ni] = *(const short8*)(xs + tl * 128 + (((s & 1) * 64 + l4 * 16) ^ SWZ(tl)));
            } else if (s < 8) {     // cond cc (s-6)*32..+32
                Bf[ni] = *(const short8*)(csA + col * 128 + (((s - 6) * 64 + l4 * 16) ^ SWZ(col)));
            } else {                // cond cc 64..79 (half-K; l4>=2 lanes have zero A)
                Bf[ni] = *(const short8*)(csB + col * 32 +
                                          (((l4 & 1) * 16) ^ ((((uint)col >> 2) & 1) << 4)));
            }
        }
        #pragma unroll
        for (int m = 0; m < 4; ++m) {
            #pragma unroll
            for (int ni = 0; ni < 2; ++ni) {
                accA[m][ni] = __builtin_amdgcn_mfma_f32_16x16x32_bf16(Aa[m], Bf[ni], accA[m][ni], 0, 0, 0);
                accG[m][ni] = __builtin_amdgcn_mfma_f32_16x16x32_bf16(Ag[m], Bf[ni], accG[m][ni], 0, 0, 0);
            }
        }
        #pragma unroll
        for (int m = 0; m < 4; ++m) { Aa[m] = An[m]; Ag[m] = Gn[m]; }
    }

    // ======== gate (register-only) + skip store + z -> LDS (overlay csA) =====
    char* zs = csA;    // [32 t][64 r] bf16, 128-B rows, SWZ on t; csA reads done
    #pragma unroll
    for (int m = 0; m < 4; ++m) {
        int rb = m * 16 + l4 * 4;
        #pragma unroll
        for (int ni = 0; ni < 2; ++ni) {
            int col = ni * 16 + l15;
            float z[4];
            #pragma unroll
            for (int j = 0; j < 4; ++j) {
                float a = accA[m][ni][j], g = accG[m][ni][j];
                float th = 1.f - 2.f * __builtin_amdgcn_rcpf(__expf(2.f * a) + 1.f);
                float sg = __builtin_amdgcn_rcpf(1.f + __expf(-g));
                z[j] = th * sg;
                skip[(size_t)(b * 64 + rb + j) * T_LEN + t0 + col] = z[j];
            }
            uint2v p = {pk2(z[0], z[1]), pk2(z[2], z[3])};
            *(uint2v*)(zs + col * 128 + ((uint)(rb * 2) ^ SWZ(col))) = p;
        }
    }

    // ======== phase B: out = Wout @ z + bout (M=64, N=32, K=64) ==============
    f32x4 accO[4][2];
    #pragma unroll
    for (int m = 0; m < 4; ++m) {
        f32x4 bo = *(const f32x4*)(bout + m * 16 + l4 * 4);
        accO[m][0] = bo; accO[m][1] = bo;
    }
    short8 Ao[4];
    #pragma unroll
    for (int m = 0; m < 4; ++m) Ao[m] = pW[4352 + m * 64 + lane];
    #pragma unroll
    for (int s2 = 0; s2 < 2; ++s2) {
        short8 Aon[4];
        #pragma unroll
        for (int m = 0; m < 4; ++m) Aon[m] = zero8;
        if (s2 == 0) {
            #pragma unroll
            for (int m = 0; m < 4; ++m) Aon[m] = pW[4352 + (4 + m) * 64 + lane];
        }
        short8 Bf[2];
        #pragma unroll
        for (int ni = 0; ni < 2; ++ni) {
            int col = ni * 16 + l15;
            Bf[ni] = *(const short8*)(zs + col * 128 + ((s2 * 64 + l4 * 16) ^ SWZ(col)));
        }
        #pragma unroll
        for (int m = 0; m < 4; ++m) {
            #pragma unroll
            for (int ni = 0; ni < 2; ++ni)
                accO[m][ni] = __builtin_amdgcn_mfma_f32_16x16x32_bf16(Ao[m], Bf[ni], accO[m][ni], 0, 0, 0);
        }
        #pragma unroll
        for (int m = 0; m < 4; ++m) Ao[m] = Aon[m];
    }
    #pragma unroll
    for (int m = 0; m < 4; ++m) {
        int rb = m * 16 + l4 * 4;
        #pragma unroll
        for (int ni = 0; ni < 2; ++ni) {
            int col = ni * 16 + l15;
            #pragma unroll
            for (int j = 0; j < 4; ++j)
                out[(size_t)(b * 64 + rb + j) * T_LEN + t0 + col] = accO[m][ni][j];
        }
    }
}

extern "C" void kernel_launch(void* const* d_in, const int* in_sizes, int n_in,
                              void* d_out, int out_size, void* d_ws, size_t ws_size,
                              hipStream_t stream) {
    const float* x     = (const float*)d_in[0];
    const float* cond  = (const float*)d_in[1];
    const float* wconv = (const float*)d_in[2];
    const float* bconv = (const float*)d_in[3];
    const float* wout  = (const float*)d_in[4];
    const float* bout  = (const float*)d_in[5];
    const float* wcond = (const float*)d_in[6];

    float* out  = (float*)d_out;
    float* skip = out + (size_t)8 * 64 * T_LEN;   // outputs concatenated in return order

    pack_weights<<<dim3(152), 256, 0, stream>>>(wconv, wcond, wout);
    wavenet_wave<<<dim3(2048), 256, 0, stream>>>(x, cond, bconv, bout, out, skip);
}

// Round 13
// 74.130 us; speedup vs baseline: 1.2732x; 1.2732x over previous
//
#include <hip/hip_runtime.h>

#define T_LEN 32768
#define TT 64
#define SWZ(row) ((((row) >> 1) & 7) << 4)

// LDS layout (bytes): xs 80*128, csA 64*128, csB 64*32
#define XS_OFF   0
#define CSA_OFF  10240
#define CSB_OFF  18432
#define LDS_SZ   20480

typedef unsigned short ushort;
typedef unsigned int uint;
typedef __attribute__((ext_vector_type(8))) short short8;   // 8 bf16
typedef __attribute__((ext_vector_type(4))) float f32x4;
typedef __attribute__((ext_vector_type(2))) uint uint2v;
typedef __attribute__((ext_vector_type(4))) uint uint4v;

// Fragment-packed bf16 weights (one linear blob, L2-resident, read by all blocks).
// ushort layout: [0,32768) A1 full k-steps; [32768,34816) A8 half-frags; [34816,38912) A2.
__device__ __align__(16) ushort g_packAll[38912];

static __device__ __forceinline__ ushort f2bf(float f) {    // RNE f32->bf16 (host-side pack only)
    uint u = __float_as_uint(f);
    u += 0x7fffu + ((u >> 16) & 1u);
    return (ushort)(u >> 16);
}
// 1-inst RNE pack of two f32 -> 2xbf16 (lo in bits[15:0], hi in bits[31:16])
static __device__ __forceinline__ uint cvtpk(float lo, float hi) {
    uint r;
    asm("v_cvt_pk_bf16_f32 %0, %1, %2" : "=v"(r) : "v"(lo), "v"(hi));
    return r;
}

// A-frag (16x16x32): lane l holds A[16m + (l&15)][32s + (l>>4)*8 + j]
__global__ void pack_weights(const float* __restrict__ wconv,
                             const float* __restrict__ wcond,
                             const float* __restrict__ wout) {
    int idx = blockIdx.x * 256 + threadIdx.x;
    if (idx >= 38912) return;
    float v;
    if (idx < 32768) {                   // A1 full k-steps s=0..7 (conv 6 + cond 2)
        int j = idx & 7, lane = (idx >> 3) & 63, f = idx >> 9;  // f = s*8+g
        int s = f >> 3, g = f & 7;
        int row = (g & 3) * 16 + (lane & 15) + ((g & 4) ? 64 : 0);
        int k = s * 32 + (lane >> 4) * 8 + j;
        if (k < 192) v = wconv[row * 192 + (k & 63) * 3 + (k >> 6)];  // tap-major k
        else         v = wcond[row * 80 + (k - 192)];
    } else if (idx < 34816) {            // s=8 half-frags: k = cc 64..79 (l4<2 lanes)
        int e = idx - 32768;
        int j = e & 7, lane32 = (e >> 3) & 31, g = e >> 8;
        int row = (g & 3) * 16 + (lane32 & 15) + ((g & 4) ? 64 : 0);
        v = wcond[row * 80 + 64 + (lane32 >> 4) * 8 + j];
    } else {                             // A2: wout, f2 = s2*4 + m
        int e = idx - 34816;
        int j = e & 7, lane = (e >> 3) & 63, f2 = e >> 9;
        int row = (f2 & 3) * 16 + (lane & 15);
        v = wout[row * 64 + (f2 >> 2) * 32 + (lane >> 4) * 8 + j];
    }
    g_packAll[idx] = f2bf(v);
}

// 4096 blocks x 256 threads (4 waves), one 64-t tile each. Wave wv owns ONE
// row-pair (rows wv*16..+16 and +64) over all 64 t; 2 A-frag loads : 8 MFMAs.
// R13: (1) NT stores for out/skip -> outputs bypass L2/L3, inputs stay
// L3-resident across replays (FETCH tell); (2) v_cvt_pk_bf16_f32 for all
// f32->bf16 packing, ~300 VALU/thread cut (VALUBusy tell).
__global__ __launch_bounds__(256, 4) void wavenet_mfma(
    const float* __restrict__ x, const float* __restrict__ cond,
    const float* __restrict__ bconv, const float* __restrict__ bout,
    float* __restrict__ out, float* __restrict__ skip)
{
    __shared__ __align__(16) char lds[LDS_SZ];
    const int tid = threadIdx.x;
    // XCD-aware swizzle: 512 consecutive t-tiles per XCD (bijective, 4096 % 8 == 0)
    const int bid = ((blockIdx.x & 7) << 9) | (blockIdx.x >> 3);
    const int b   = bid >> 9;
    const int t0  = (bid & 511) * TT;

    // ---- staging items: 0..159 x(oct,tq), 160..287 csA, 288..319 csB ----
    auto item_load = [&](int i, f32x4* v) {
        const float* p;
        bool ok = true;
        if (i < 160) {
            int oct = i & 7, tq = i >> 3;
            int g0 = t0 - 16 + tq * 4;
            ok = (g0 >= 0);
            p = x + (size_t)(b * 64 + oct * 8) * T_LEN + g0;
        } else if (i < 288) {
            int e = i - 160; int oct = e & 7, tq = e >> 3;
            p = cond + (size_t)(b * 80 + oct * 8) * T_LEN + t0 + tq * 4;
        } else {
            int e = i - 288; int octl = e & 1, tq = e >> 1;
            p = cond + (size_t)(b * 80 + 64 + octl * 8) * T_LEN + t0 + tq * 4;
        }
        if (ok) {
            #pragma unroll
            for (int j = 0; j < 8; ++j) v[j] = *(const f32x4*)(p + (size_t)j * T_LEN);
        } else {
            #pragma unroll
            for (int j = 0; j < 8; ++j) v[j] = (f32x4){0.f, 0.f, 0.f, 0.f};
        }
    };
    auto item_write = [&](int i, const f32x4* v) {
        char* basep; int tl, chunk; bool isB = false;
        if (i < 160)      { basep = lds + XS_OFF;  tl = (i >> 3) * 4;               chunk = (i & 7) * 16; }
        else if (i < 288) { int e = i - 160; basep = lds + CSA_OFF; tl = (e >> 3) * 4; chunk = (e & 7) * 16; }
        else              { int e = i - 288; basep = lds + CSB_OFF; tl = (e >> 1) * 4; chunk = (e & 1) * 16; isB = true; }
        #pragma unroll
        for (int r = 0; r < 4; ++r) {
            uint4v pk;
            #pragma unroll
            for (int q = 0; q < 4; ++q)
                pk[q] = cvtpk(v[2 * q][r], v[2 * q + 1][r]);   // ch 2q lo, 2q+1 hi
            int row = tl + r;
            int byte = isB ? row * 32 + (chunk ^ (((row >> 2) & 1) << 4))
                           : row * 128 + (chunk ^ SWZ(row));
            *(uint4v*)(basep + byte) = pk;
        }
    };

    // coverage: items [0,320), stride-256 loop
    for (int i = tid; i < 320; i += 256) {
        f32x4 va[8];
        item_load(i, va);
        item_write(i, va);
    }
    __syncthreads();

    const int lane = tid & 63, wv = tid >> 6;
    const int l4 = lane >> 4, l15 = lane & 15;
    const int rb = wv * 16 + l4 * 4;              // row base within each 64-row half
    const short8* pW = (const short8*)g_packAll;  // A1 at frag 0, A8 at 4096, A2 at 4352
    const short8 zero8 = (short8){0, 0, 0, 0, 0, 0, 0, 0};

    // ---- phase A: y = conv(*)x + Wcond*c + bconv ----
    f32x4 accA[4], accG[4];
    {
        f32x4 ba = *(const f32x4*)(bconv + rb);
        f32x4 bg = *(const f32x4*)(bconv + 64 + rb);
        #pragma unroll
        for (int ni = 0; ni < 4; ++ni) { accA[ni] = ba; accG[ni] = bg; }
    }

    short8 Aa = pW[(0 * 8 + wv) * 64 + lane];
    short8 Ag = pW[(0 * 8 + 4 + wv) * 64 + lane];
    #pragma unroll
    for (int s = 0; s < 9; ++s) {
        short8 Aan = zero8, Agn = zero8;
        if (s < 7) {                     // prefetch next full k-step
            Aan = pW[((s + 1) * 8 + wv) * 64 + lane];
            Agn = pW[((s + 1) * 8 + 4 + wv) * 64 + lane];
        } else if (s == 7) {             // prefetch s=8 half-frag (lanes l4<2 only)
            if (l4 < 2) {
                Aan = pW[4096 + wv * 32 + lane];
                Agn = pW[4096 + (4 + wv) * 32 + lane];
            }
        }
        short8 B[4];
        #pragma unroll
        for (int ni = 0; ni < 4; ++ni) {
            int col = ni * 16 + l15;
            if (s < 6) {            // conv tap s>>1, c-half s&1; tap shifts t by 8*tap
                int tl = col + (s >> 1) * 8;
                B[ni] = *(const short8*)(lds + XS_OFF + tl * 128 + (((s & 1) * 64 + l4 * 16) ^ SWZ(tl)));
            } else if (s < 8) {     // cond cc (s-6)*32..+32
                B[ni] = *(const short8*)(lds + CSA_OFF + col * 128 + (((s - 6) * 64 + l4 * 16) ^ SWZ(col)));
            } else {                // cond cc 64..79 (half-K; l4>=2 lanes have zero A)
                B[ni] = *(const short8*)(lds + CSB_OFF + col * 32 + (((l4 & 1) * 16) ^ (((col >> 2) & 1) << 4)));
            }
        }
        #pragma unroll
        for (int ni = 0; ni < 4; ++ni) {
            accA[ni] = __builtin_amdgcn_mfma_f32_16x16x32_bf16(Aa, B[ni], accA[ni], 0, 0, 0);
            accG[ni] = __builtin_amdgcn_mfma_f32_16x16x32_bf16(Ag, B[ni], accG[ni], 0, 0, 0);
        }
        Aa = Aan; Ag = Agn;
    }
    __syncthreads();   // xs/csA/csB reads done -> zs may overlay

    // ---- gate (register-only) + NT skip store + z -> LDS ----
    char* zs = lds + XS_OFF;    // [64 t][64 r] bf16, 128B rows, SWZ on t
    #pragma unroll
    for (int ni = 0; ni < 4; ++ni) {
        int col = ni * 16 + l15;
        float z[4];
        #pragma unroll
        for (int j = 0; j < 4; ++j) {
            float a = accA[ni][j], g = accG[ni][j];
            float th = 1.f - 2.f * __builtin_amdgcn_rcpf(__expf(2.f * a) + 1.f);
            float sg = __builtin_amdgcn_rcpf(1.f + __expf(-g));
            z[j] = th * sg;
            __builtin_nontemporal_store(z[j], &skip[(size_t)(b * 64 + rb + j) * T_LEN + t0 + col]);
        }
        uint2v p = {cvtpk(z[0], z[1]), cvtpk(z[2], z[3])};
        *(uint2v*)(zs + col * 128 + ((uint)(rb * 2) ^ SWZ(col))) = p;
    }
    __syncthreads();

    // ---- phase B: out = Wout @ z + bout (wave wv: M-frag wv x 4 N-frags) ----
    f32x4 accO[4];
    {
        f32x4 bo = *(const f32x4*)(bout + rb);
        #pragma unroll
        for (int ni = 0; ni < 4; ++ni) accO[ni] = bo;
    }
    short8 Ao = pW[4352 + (0 * 4 + wv) * 64 + lane];
    #pragma unroll
    for (int s2 = 0; s2 < 2; ++s2) {
        short8 Aon = zero8;
        if (s2 == 0) Aon = pW[4352 + (1 * 4 + wv) * 64 + lane];
        short8 B[4];
        #pragma unroll
        for (int ni = 0; ni < 4; ++ni) {
            int col = ni * 16 + l15;
            B[ni] = *(const short8*)(zs + col * 128 + ((s2 * 64 + l4 * 16) ^ SWZ(col)));
        }
        #pragma unroll
        for (int ni = 0; ni < 4; ++ni)
            accO[ni] = __builtin_amdgcn_mfma_f32_16x16x32_bf16(Ao, B[ni], accO[ni], 0, 0, 0);
        Ao = Aon;
    }
    #pragma unroll
    for (int ni = 0; ni < 4; ++ni) {
        int col = ni * 16 + l15;
        #pragma unroll
        for (int j = 0; j < 4; ++j)
            __builtin_nontemporal_store(accO[ni][j],
                &out[(size_t)(b * 64 + rb + j) * T_LEN + t0 + col]);
    }
}

extern "C" void kernel_launch(void* const* d_in, const int* in_sizes, int n_in,
                              void* d_out, int out_size, void* d_ws, size_t ws_size,
                              hipStream_t stream) {
    const float* x     = (const float*)d_in[0];
    const float* cond  = (const float*)d_in[1];
    const float* wconv = (const float*)d_in[2];
    const float* bconv = (const float*)d_in[3];
    const float* wout  = (const float*)d_in[4];
    const float* bout  = (const float*)d_in[5];
    const float* wcond = (const float*)d_in[6];

    float* out  = (float*)d_out;
    float* skip = out + (size_t)8 * 64 * T_LEN;   // outputs concatenated in return order

    pack_weights<<<dim3(152), 256, 0, stream>>>(wconv, wcond, wout);
    wavenet_mfma<<<dim3(8 * (T_LEN / TT)), 256, 0, stream>>>(x, cond, bconv, bout, out, skip);
}

// Round 14
// 73.146 us; speedup vs baseline: 1.2903x; 1.0134x over previous
//
#include <hip/hip_runtime.h>

#define T_LEN 32768
#define TT 64
#define SWZ(row) ((((row) >> 1) & 7) << 4)

// LDS layout (bytes): xs 80*128, csA 64*128, csB 64*32
#define XS_OFF   0
#define CSA_OFF  10240
#define CSB_OFF  18432
#define LDS_SZ   20480

typedef unsigned short ushort;
typedef unsigned int uint;
typedef __attribute__((ext_vector_type(8))) short short8;   // 8 bf16
typedef __attribute__((ext_vector_type(4))) float f32x4;
typedef __attribute__((ext_vector_type(2))) uint uint2v;
typedef __attribute__((ext_vector_type(4))) uint uint4v;

// Fragment-packed bf16 weights (one linear blob, L2-resident, read by all blocks).
// ushort layout: [0,32768) A1 full k-steps; [32768,34816) A8 half-frags; [34816,38912) A2.
__device__ __align__(16) ushort g_packAll[38912];

static __device__ __forceinline__ ushort f2bf(float f) {    // RNE f32->bf16 (pack kernel only)
    uint u = __float_as_uint(f);
    u += 0x7fffu + ((u >> 16) & 1u);
    return (ushort)(u >> 16);
}
// 1-inst RNE pack of two f32 -> 2xbf16 (lo in bits[15:0], hi in bits[31:16])
static __device__ __forceinline__ uint cvtpk(float lo, float hi) {
    uint r;
    asm("v_cvt_pk_bf16_f32 %0, %1, %2" : "=v"(r) : "v"(lo), "v"(hi));
    return r;
}

// A-frag (16x16x32): lane l holds A[16m + (l&15)][32s + (l>>4)*8 + j]
// (B-frag has the identical lane->(16-dim, k-octet) addressing, so the A2 blob
//  doubles as Wout^T B-fragments for the swapped phase B.)
__global__ void pack_weights(const float* __restrict__ wconv,
                             const float* __restrict__ wcond,
                             const float* __restrict__ wout) {
    int idx = blockIdx.x * 256 + threadIdx.x;
    if (idx >= 38912) return;
    float v;
    if (idx < 32768) {                   // A1 full k-steps s=0..7 (conv 6 + cond 2)
        int j = idx & 7, lane = (idx >> 3) & 63, f = idx >> 9;  // f = s*8+g
        int s = f >> 3, g = f & 7;
        int row = (g & 3) * 16 + (lane & 15) + ((g & 4) ? 64 : 0);
        int k = s * 32 + (lane >> 4) * 8 + j;
        if (k < 192) v = wconv[row * 192 + (k & 63) * 3 + (k >> 6)];  // tap-major k
        else         v = wcond[row * 80 + (k - 192)];
    } else if (idx < 34816) {            // s=8 half-frags: k = cc 64..79 (l4<2 lanes)
        int e = idx - 32768;
        int j = e & 7, lane32 = (e >> 3) & 31, g = e >> 8;
        int row = (g & 3) * 16 + (lane32 & 15) + ((g & 4) ? 64 : 0);
        v = wcond[row * 80 + 64 + (lane32 >> 4) * 8 + j];
    } else {                             // A2: wout, f2 = s2*4 + m
        int e = idx - 34816;
        int j = e & 7, lane = (e >> 3) & 63, f2 = e >> 9;
        int row = (f2 & 3) * 16 + (lane & 15);
        v = wout[row * 64 + (f2 >> 2) * 32 + (lane >> 4) * 8 + j];
    }
    g_packAll[idx] = f2bf(v);
}

// 4096 blocks x 256 threads (4 waves), one 64-t tile each. Wave wv owns ONE
// row-pair (rows wv*16..+16 and +64) over all 64 t; 2 A-frag loads : 8 MFMAs.
// R14: phase B computes out^T = z^T * Wout^T (swapped MFMA operands) so each
// lane holds 4 consecutive t of one channel -> per-lane f32x4 NT stores
// (16 dword -> 4 dwordx4 per thread). zs reads and A2 bytes are unchanged.
__global__ __launch_bounds__(256, 4) void wavenet_mfma(
    const float* __restrict__ x, const float* __restrict__ cond,
    const float* __restrict__ bconv, const float* __restrict__ bout,
    float* __restrict__ out, float* __restrict__ skip)
{
    __shared__ __align__(16) char lds[LDS_SZ];
    const int tid = threadIdx.x;
    // XCD-aware swizzle: 512 consecutive t-tiles per XCD (bijective, 4096 % 8 == 0)
    const int bid = ((blockIdx.x & 7) << 9) | (blockIdx.x >> 3);
    const int b   = bid >> 9;
    const int t0  = (bid & 511) * TT;

    // ---- staging items: 0..159 x(oct,tq), 160..287 csA, 288..319 csB ----
    auto item_load = [&](int i, f32x4* v) {
        const float* p;
        bool ok = true;
        if (i < 160) {
            int oct = i & 7, tq = i >> 3;
            int g0 = t0 - 16 + tq * 4;
            ok = (g0 >= 0);
            p = x + (size_t)(b * 64 + oct * 8) * T_LEN + g0;
        } else if (i < 288) {
            int e = i - 160; int oct = e & 7, tq = e >> 3;
            p = cond + (size_t)(b * 80 + oct * 8) * T_LEN + t0 + tq * 4;
        } else {
            int e = i - 288; int octl = e & 1, tq = e >> 1;
            p = cond + (size_t)(b * 80 + 64 + octl * 8) * T_LEN + t0 + tq * 4;
        }
        if (ok) {
            #pragma unroll
            for (int j = 0; j < 8; ++j) v[j] = *(const f32x4*)(p + (size_t)j * T_LEN);
        } else {
            #pragma unroll
            for (int j = 0; j < 8; ++j) v[j] = (f32x4){0.f, 0.f, 0.f, 0.f};
        }
    };
    auto item_write = [&](int i, const f32x4* v) {
        char* basep; int tl, chunk; bool isB = false;
        if (i < 160)      { basep = lds + XS_OFF;  tl = (i >> 3) * 4;               chunk = (i & 7) * 16; }
        else if (i < 288) { int e = i - 160; basep = lds + CSA_OFF; tl = (e >> 3) * 4; chunk = (e & 7) * 16; }
        else              { int e = i - 288; basep = lds + CSB_OFF; tl = (e >> 1) * 4; chunk = (e & 1) * 16; isB = true; }
        #pragma unroll
        for (int r = 0; r < 4; ++r) {
            uint4v pk;
            #pragma unroll
            for (int q = 0; q < 4; ++q)
                pk[q] = cvtpk(v[2 * q][r], v[2 * q + 1][r]);   // ch 2q lo, 2q+1 hi
            int row = tl + r;
            int byte = isB ? row * 32 + (chunk ^ (((row >> 2) & 1) << 4))
                           : row * 128 + (chunk ^ SWZ(row));
            *(uint4v*)(basep + byte) = pk;
        }
    };

    // coverage: items [0,320), stride-256 loop
    for (int i = tid; i < 320; i += 256) {
        f32x4 va[8];
        item_load(i, va);
        item_write(i, va);
    }
    __syncthreads();

    const int lane = tid & 63, wv = tid >> 6;
    const int l4 = lane >> 4, l15 = lane & 15;
    const int rb = wv * 16 + l4 * 4;              // row base within each 64-row half
    const short8* pW = (const short8*)g_packAll;  // A1 at frag 0, A8 at 4096, A2 at 4352
    const short8 zero8 = (short8){0, 0, 0, 0, 0, 0, 0, 0};

    // ---- phase A: y = conv(*)x + Wcond*c + bconv ----
    f32x4 accA[4], accG[4];
    {
        f32x4 ba = *(const f32x4*)(bconv + rb);
        f32x4 bg = *(const f32x4*)(bconv + 64 + rb);
        #pragma unroll
        for (int ni = 0; ni < 4; ++ni) { accA[ni] = ba; accG[ni] = bg; }
    }

    short8 Aa = pW[(0 * 8 + wv) * 64 + lane];
    short8 Ag = pW[(0 * 8 + 4 + wv) * 64 + lane];
    #pragma unroll
    for (int s = 0; s < 9; ++s) {
        short8 Aan = zero8, Agn = zero8;
        if (s < 7) {                     // prefetch next full k-step
            Aan = pW[((s + 1) * 8 + wv) * 64 + lane];
            Agn = pW[((s + 1) * 8 + 4 + wv) * 64 + lane];
        } else if (s == 7) {             // prefetch s=8 half-frag (lanes l4<2 only)
            if (l4 < 2) {
                Aan = pW[4096 + wv * 32 + lane];
                Agn = pW[4096 + (4 + wv) * 32 + lane];
            }
        }
        short8 B[4];
        #pragma unroll
        for (int ni = 0; ni < 4; ++ni) {
            int col = ni * 16 + l15;
            if (s < 6) {            // conv tap s>>1, c-half s&1; tap shifts t by 8*tap
                int tl = col + (s >> 1) * 8;
                B[ni] = *(const short8*)(lds + XS_OFF + tl * 128 + (((s & 1) * 64 + l4 * 16) ^ SWZ(tl)));
            } else if (s < 8) {     // cond cc (s-6)*32..+32
                B[ni] = *(const short8*)(lds + CSA_OFF + col * 128 + (((s - 6) * 64 + l4 * 16) ^ SWZ(col)));
            } else {                // cond cc 64..79 (half-K; l4>=2 lanes have zero A)
                B[ni] = *(const short8*)(lds + CSB_OFF + col * 32 + (((l4 & 1) * 16) ^ (((col >> 2) & 1) << 4)));
            }
        }
        #pragma unroll
        for (int ni = 0; ni < 4; ++ni) {
            accA[ni] = __builtin_amdgcn_mfma_f32_16x16x32_bf16(Aa, B[ni], accA[ni], 0, 0, 0);
            accG[ni] = __builtin_amdgcn_mfma_f32_16x16x32_bf16(Ag, B[ni], accG[ni], 0, 0, 0);
        }
        Aa = Aan; Ag = Agn;
    }
    __syncthreads();   // xs/csA/csB reads done -> zs may overlay

    // ---- gate (register-only) + NT skip store + z -> LDS ----
    char* zs = lds + XS_OFF;    // [64 t][64 r] bf16, 128B rows, SWZ on t
    #pragma unroll
    for (int ni = 0; ni < 4; ++ni) {
        int col = ni * 16 + l15;
        float z[4];
        #pragma unroll
        for (int j = 0; j < 4; ++j) {
            float a = accA[ni][j], g = accG[ni][j];
            float th = 1.f - 2.f * __builtin_amdgcn_rcpf(__expf(2.f * a) + 1.f);
            float sg = __builtin_amdgcn_rcpf(1.f + __expf(-g));
            z[j] = th * sg;
            __builtin_nontemporal_store(z[j], &skip[(size_t)(b * 64 + rb + j) * T_LEN + t0 + col]);
        }
        uint2v p = {cvtpk(z[0], z[1]), cvtpk(z[2], z[3])};
        *(uint2v*)(zs + col * 128 + ((uint)(rb * 2) ^ SWZ(col))) = p;
    }
    __syncthreads();

    // ---- phase B (swapped): out^T[t][ch] = z^T * Wout^T + bout ----
    // A-operand = z^T frag (same bytes as the old B-read of zs, indexed by tf);
    // B-operand = Wout^T frag (same A2 bytes as before, indexed by wv).
    // D: col = ch-in-frag (l15), row = t-in-frag (l4*4 + j) -> f32x4 along t.
    const float bo_s = bout[wv * 16 + l15];
    f32x4 accO[4];
    #pragma unroll
    for (int tf = 0; tf < 4; ++tf) accO[tf] = (f32x4){bo_s, bo_s, bo_s, bo_s};

    short8 Bw = pW[4352 + (0 * 4 + wv) * 64 + lane];
    #pragma unroll
    for (int s2 = 0; s2 < 2; ++s2) {
        short8 Bwn = zero8;
        if (s2 == 0) Bwn = pW[4352 + (1 * 4 + wv) * 64 + lane];
        #pragma unroll
        for (int tf = 0; tf < 4; ++tf) {
            int colt = tf * 16 + l15;
            short8 Az = *(const short8*)(zs + colt * 128 + ((s2 * 64 + l4 * 16) ^ SWZ(colt)));
            accO[tf] = __builtin_amdgcn_mfma_f32_16x16x32_bf16(Az, Bw, accO[tf], 0, 0, 0);
        }
        Bw = Bwn;
    }
    #pragma unroll
    for (int tf = 0; tf < 4; ++tf) {
        size_t ch = (size_t)(b * 64 + wv * 16 + l15);
        int tg = t0 + tf * 16 + l4 * 4;
        __builtin_nontemporal_store(accO[tf], (f32x4*)&out[ch * T_LEN + tg]);
    }
}

extern "C" void kernel_launch(void* const* d_in, const int* in_sizes, int n_in,
                              void* d_out, int out_size, void* d_ws, size_t ws_size,
                              hipStream_t stream) {
    const float* x     = (const float*)d_in[0];
    const float* cond  = (const float*)d_in[1];
    const float* wconv = (const float*)d_in[2];
    const float* bconv = (const float*)d_in[3];
    const float* wout  = (const float*)d_in[4];
    const float* bout  = (const float*)d_in[5];
    const float* wcond = (const float*)d_in[6];

    float* out  = (float*)d_out;
    float* skip = out + (size_t)8 * 64 * T_LEN;   // outputs concatenated in return order

    pack_weights<<<dim3(152), 256, 0, stream>>>(wconv, wcond, wout);
    wavenet_mfma<<<dim3(8 * (T_LEN / TT)), 256, 0, stream>>>(x, cond, bconv, bout, out, skip);
}